// Round 3
// baseline (408.724 us; speedup 1.0000x reference)
//
#include <hip/hip_runtime.h>
#include <math.h>

#define B_SZ 1024
#define K_SZ 24
#define H_SZ 64

typedef float vfloat4 __attribute__((ext_vector_type(4)));

// ---------------------------------------------------------------------------
// R6. Evidence so far: NT->plain (R4) null; block-shared vs wave-private (R5)
// null. Both structures inferred at ~125-140 us kernel time = ~3.3 TB/s write
// BW, vs fillBufferAligned's proven 6.2 TB/s on this very buffer -- at 10%
// occupancy (few long-lived waves, long sequential store runs).
//
// R6 theory: the 2x loss is the WRITE-STREAM SHAPE, not intra-block overhead.
// 24576 short-lived blocks (~2400 resident) each own a different 16 KB chunk
// -> instantaneous write window ~38 MB (> 32 MB aggregate L2), 16 KB-grain
// scatter across HBM channels/rows -> row-buffer thrash, ~50% efficiency.
//
// R6 fix: fill-shaped writer. Grid = 1024 blocks (one per batch b, 4/CU, all
// resident at t=0, no dispatch churn, no tail). Each block loops o=0..23 and
// emits a 384 KB fully-sequential store stream. Spikes computed once per
// block (prep kernel folded in -- single dispatch). Per plane: scatter <=600
// taps into one LDS tile; store + same-thread re-zero => 2 barriers/plane.
// Duty cycle: plane critical path ~650 cyc << 1638 cyc HBM-time/plane/CU,
// so stores stay saturated.
// ---------------------------------------------------------------------------

__global__ __launch_bounds__(256) void gs_batch(
    const float2* __restrict__ x,      // [B*K] (x,y)
    const float*  __restrict__ w,      // [K,K,5,5] OIHW
    const int*    __restrict__ vis_b,  // [256]
    const int*    __restrict__ vis_k,  // [256]
    float*        __restrict__ out)    // [B,K,64,64]
{
    __shared__ float tile[H_SZ * H_SZ];   // 16 KB accumulation plane
    __shared__ int   spike[K_SZ];         // packed y*64+x, or -1

    const int b   = blockIdx.x;
    const int tid = threadIdx.x;

    // ---- spikes for this batch (threads 0..23)
    if (tid < K_SZ) {
        const float2 c = x[b * K_SZ + tid];
        // match jnp.round((v+1)*0.5*(H-1)); rintf = round-half-to-even
        const int cx = (int)rintf((c.x + 1.0f) * 0.5f * 63.0f);
        const int cy = (int)rintf((c.y + 1.0f) * 0.5f * 63.0f);
        // in-range AND torch quirk (x != 0): cx in [1,64), cy in [0,64)
        const bool ok = (cx >= 1) & (cx < H_SZ) & (cy >= 0) & (cy < H_SZ);
        spike[tid] = ok ? (cy * H_SZ + cx) : -1;
    }

    // ---- zero the tile while spike-init lands
    vfloat4* t4 = (vfloat4*)tile;
    const vfloat4 z = {0.f, 0.f, 0.f, 0.f};
#pragma unroll
    for (int r = 0; r < 4; ++r) t4[r * 256 + tid] = z;
    __syncthreads();

    // ---- vis kill: each thread checks one vis entry against this block's b
    {
        const int code = vis_b[tid] * K_SZ + vis_k[tid];
        const unsigned local = (unsigned)(code - b * K_SZ);
        if (local < (unsigned)K_SZ) spike[local] = -1;  // racy same-value ok
    }
    __syncthreads();

    // ---- per-thread tap geometry (3 taps x 256 threads covers 600)
    int cc[3], di[3], dj[3]; bool act[3];
#pragma unroll
    for (int it = 0; it < 3; ++it) {
        const int t = tid + it * 256;
        act[it] = (t < K_SZ * 25);
        const int c = t / 25;
        const int p = t - c * 25;
        cc[it] = c;
        di[it] = p / 5;
        dj[it] = p - (p / 5) * 5;
    }

    float* outb = out + (((size_t)b * K_SZ) << 12);

    for (int o = 0; o < K_SZ; ++o) {
        const float* wo = w + o * (K_SZ * 25);

        // unconditional weight loads first (L2-hot, max MLP)
        float wv[3];
#pragma unroll
        for (int it = 0; it < 3; ++it)
            if (act[it]) wv[it] = wo[tid + it * 256];

        // scatter <=600 taps into the tile
#pragma unroll
        for (int it = 0; it < 3; ++it) {
            if (act[it]) {
                const int s = spike[cc[it]];
                if (s >= 0) {
                    const int i = (s >> 6) + 2 - di[it];
                    const int j = (s & 63) + 2 - dj[it];
                    if (((unsigned)i < H_SZ) & ((unsigned)j < H_SZ))
                        atomicAdd(&tile[i * H_SZ + j], wv[it]);
                }
            }
        }
        __syncthreads();   // scatter complete

        // store plane o (sequential within the block's 384 KB run) and
        // re-zero own cells (same thread reads then writes its own cells:
        // program order suffices, no extra barrier)
        vfloat4* o4 = (vfloat4*)(outb + ((size_t)o << 12));
#pragma unroll
        for (int r = 0; r < 4; ++r) {
            const int idx = r * 256 + tid;
            const vfloat4 v = t4[idx];
            o4[idx] = v;
            t4[idx] = z;
        }
        __syncthreads();   // zeros visible before next scatter
    }
}

extern "C" void kernel_launch(void* const* d_in, const int* in_sizes, int n_in,
                              void* d_out, int out_size, void* d_ws, size_t ws_size,
                              hipStream_t stream) {
    const float2* x     = (const float2*)d_in[0];
    const float*  w     = (const float*)d_in[1];
    const int*    vis_b = (const int*)d_in[2];
    const int*    vis_k = (const int*)d_in[3];
    float*        out   = (float*)d_out;

    gs_batch<<<B_SZ, 256, 0, stream>>>(x, w, vis_b, vis_k, out);
}